// Round 1
// baseline (134.587 us; speedup 1.0000x reference)
//
#include <hip/hip_runtime.h>
#include <hip/hip_bf16.h>

// Problem constants (from reference)
#define N_COARSE 40962
#define N_NEW    122880
#define M_TOTAL  (N_COARSE + N_NEW)   // 163842
#define CIN      256
#define COUT     256

// Tiling
#define BM 128
#define BN 128
#define BK 64
#define M_TILES ((M_TOTAL + BM - 1) / BM)   // 1281 (last tile padded)

typedef __bf16 bf16x8 __attribute__((ext_vector_type(8)));
typedef float  f32x4  __attribute__((ext_vector_type(4)));

static __device__ __forceinline__ unsigned short f2bf(float f) {
    unsigned int u = __builtin_bit_cast(unsigned int, f);
    u += 0x7FFFu + ((u >> 16) & 1u);   // round-to-nearest-even
    return (unsigned short)(u >> 16);
}

union Pk8 { unsigned short h[8]; int4 v; };

// Fused: gather/avg (bf16 convert) -> LDS -> MFMA GEMM (y = x_full @ W^T + b)
__global__ __launch_bounds__(256, 2) void unpool_linear_kernel(
    const float* __restrict__ x,      // [N_COARSE][CIN] fp32
    const int*   __restrict__ idx,    // [N_NEW][2] int32
    const float* __restrict__ W,      // [COUT][CIN] fp32
    const float* __restrict__ bias,   // [COUT] fp32
    float*       __restrict__ out)    // [M_TOTAL][COUT] fp32
{
    __shared__ __align__(16) unsigned short As[BM * BK];
    __shared__ __align__(16) unsigned short Bs[BN * BK];

    const int m0 = blockIdx.x * BM;
    const int n0 = blockIdx.y * BN;

    const int t    = threadIdx.x;
    const int lane = t & 63;
    const int wid  = t >> 6;     // 0..3
    const int wr   = wid >> 1;   // wave row-half (0/1)
    const int wc   = wid & 1;    // wave col-half (0/1)

    f32x4 acc[4][4];
#pragma unroll
    for (int i = 0; i < 4; ++i)
#pragma unroll
        for (int j = 0; j < 4; ++j)
            acc[i][j] = (f32x4){0.f, 0.f, 0.f, 0.f};

    for (int k0 = 0; k0 < CIN; k0 += BK) {
        // ---------- stage A (x_full tile) and B (W tile) into LDS as bf16 ----------
        // 1024 chunks of 8 bf16 per tile; 4 chunks/thread/tile.
#pragma unroll
        for (int i = 0; i < 4; ++i) {
            const int chunk = t + i * 256;      // 0..1023
            const int r     = chunk >> 3;       // tile row 0..127
            const int c8    = chunk & 7;        // 8-col group
            const int kcol  = k0 + c8 * 8;      // global k
            // swizzled LDS index (shorts); XOR permutes 16B slots within a row
            const int sidx = (r * BK + c8 * 8) ^ ((r & 7) << 3);

            // ---- A ----
            float v[8];
            const int gr = m0 + r;
            if (gr < N_COARSE) {
                const float* src = x + (size_t)gr * CIN + kcol;
                float4 a0 = *(const float4*)(src);
                float4 a1 = *(const float4*)(src + 4);
                v[0]=a0.x; v[1]=a0.y; v[2]=a0.z; v[3]=a0.w;
                v[4]=a1.x; v[5]=a1.y; v[6]=a1.z; v[7]=a1.w;
            } else if (gr < M_TOTAL) {
                const int j  = gr - N_COARSE;
                const int p0 = idx[2 * j];
                const int p1 = idx[2 * j + 1];
                const float* s0 = x + (size_t)p0 * CIN + kcol;
                const float* s1 = x + (size_t)p1 * CIN + kcol;
                float4 a0 = *(const float4*)(s0);
                float4 a1 = *(const float4*)(s0 + 4);
                float4 b0 = *(const float4*)(s1);
                float4 b1 = *(const float4*)(s1 + 4);
                v[0]=(a0.x+b0.x)*0.5f; v[1]=(a0.y+b0.y)*0.5f;
                v[2]=(a0.z+b0.z)*0.5f; v[3]=(a0.w+b0.w)*0.5f;
                v[4]=(a1.x+b1.x)*0.5f; v[5]=(a1.y+b1.y)*0.5f;
                v[6]=(a1.z+b1.z)*0.5f; v[7]=(a1.w+b1.w)*0.5f;
            } else {
#pragma unroll
                for (int q = 0; q < 8; ++q) v[q] = 0.f;
            }
            Pk8 pa;
#pragma unroll
            for (int q = 0; q < 8; ++q) pa.h[q] = f2bf(v[q]);
            *(int4*)&As[sidx] = pa.v;

            // ---- B (W rows n0+r, same k slice) ----
            const float* ws = W + (size_t)(n0 + r) * CIN + kcol;
            float4 w0 = *(const float4*)(ws);
            float4 w1 = *(const float4*)(ws + 4);
            Pk8 pb;
            pb.h[0]=f2bf(w0.x); pb.h[1]=f2bf(w0.y); pb.h[2]=f2bf(w0.z); pb.h[3]=f2bf(w0.w);
            pb.h[4]=f2bf(w1.x); pb.h[5]=f2bf(w1.y); pb.h[6]=f2bf(w1.z); pb.h[7]=f2bf(w1.w);
            *(int4*)&Bs[sidx] = pb.v;
        }
        __syncthreads();

        // ---------- MFMA over this K-slice ----------
#pragma unroll
        for (int kk = 0; kk < BK; kk += 32) {
            const int kcol = kk + 8 * (lane >> 4);
            bf16x8 af[4], bfv[4];
#pragma unroll
            for (int i = 0; i < 4; ++i) {
                const int r    = wr * 64 + i * 16 + (lane & 15);
                const int sidx = (r * BK + kcol) ^ ((r & 7) << 3);
                af[i] = __builtin_bit_cast(bf16x8, *(const int4*)&As[sidx]);
            }
#pragma unroll
            for (int j = 0; j < 4; ++j) {
                const int r    = wc * 64 + j * 16 + (lane & 15);
                const int sidx = (r * BK + kcol) ^ ((r & 7) << 3);
                bfv[j] = __builtin_bit_cast(bf16x8, *(const int4*)&Bs[sidx]);
            }
#pragma unroll
            for (int i = 0; i < 4; ++i)
#pragma unroll
                for (int j = 0; j < 4; ++j)
                    acc[i][j] = __builtin_amdgcn_mfma_f32_16x16x32_bf16(
                        af[i], bfv[j], acc[i][j], 0, 0, 0);
        }
        __syncthreads();
    }

    // ---------- epilogue: bias + fp32 store ----------
    // C/D layout (verified m89/m91): col = lane&15, row = (lane>>4)*4 + reg
    const int colbase = n0 + wc * 64 + (lane & 15);
    const int rowbase = m0 + wr * 64 + ((lane >> 4) << 2);
#pragma unroll
    for (int j = 0; j < 4; ++j) {
        const int col = colbase + j * 16;
        const float bv = bias[col];
#pragma unroll
        for (int i = 0; i < 4; ++i) {
            const int row = rowbase + i * 16;
#pragma unroll
            for (int r2 = 0; r2 < 4; ++r2) {
                const int rr = row + r2;
                if (rr < M_TOTAL)
                    out[(size_t)rr * COUT + col] = acc[i][j][r2] + bv;
            }
        }
    }
}

extern "C" void kernel_launch(void* const* d_in, const int* in_sizes, int n_in,
                              void* d_out, int out_size, void* d_ws, size_t ws_size,
                              hipStream_t stream) {
    const float* x    = (const float*)d_in[0];
    const int*   idx  = (const int*)d_in[1];   // harness delivers integer inputs as int32
    const float* W    = (const float*)d_in[2];
    const float* bias = (const float*)d_in[3];
    float* out = (float*)d_out;

    dim3 grid(M_TILES, COUT / BN);   // (1281, 2)
    unpool_linear_kernel<<<grid, 256, 0, stream>>>(x, idx, W, bias, out);
}

// Round 2
// 121.436 us; speedup vs baseline: 1.1083x; 1.1083x over previous
//
#include <hip/hip_runtime.h>
#include <hip/hip_bf16.h>

// Problem constants (from reference)
#define N_COARSE 40962
#define N_NEW    122880
#define M_TOTAL  (N_COARSE + N_NEW)   // 163842
#define CIN      256
#define COUT     256

// GEMM tiling (phase 2)
#define BM 128
#define BN 256
#define BK 64
#define MT      ((M_TOTAL + BM - 1) / BM)       // 1281
#define XB_ROWS (MT * BM)                       // 163968 (padded)
#define XB_BYTES ((size_t)XB_ROWS * CIN * 2)    // 83,951,616
#define WB_BYTES ((size_t)COUT * CIN * 2)       // 131,072

typedef __bf16 bf16x8 __attribute__((ext_vector_type(8)));
typedef float  f32x4  __attribute__((ext_vector_type(4)));

static __device__ __forceinline__ unsigned short f2bf(float f) {
    unsigned int u = __builtin_bit_cast(unsigned int, f);
    u += 0x7FFFu + ((u >> 16) & 1u);   // round-to-nearest-even
    return (unsigned short)(u >> 16);
}

#define GLOAD16(gp, lp)                                                        \
    __builtin_amdgcn_global_load_lds(                                          \
        (const __attribute__((address_space(1))) unsigned int*)(gp),           \
        (__attribute__((address_space(3))) unsigned int*)(lp), 16, 0, 0)

// ---------------------------------------------------------------------------
// Phase 1: gather/average + fp32->bf16 convert of x_full; convert W to bf16.
// One wave per row. Fully coalesced: 64 lanes x float4 in, 64 x short4 out.
// ---------------------------------------------------------------------------
__global__ __launch_bounds__(256) void prep_kernel(
    const float* __restrict__ x,     // [N_COARSE][CIN]
    const int*   __restrict__ idx,   // [N_NEW][2]
    const float* __restrict__ W,     // [COUT][CIN]
    unsigned short* __restrict__ xb, // [XB_ROWS][CIN] bf16
    unsigned short* __restrict__ wb) // [COUT][CIN] bf16
{
    const int gw   = (blockIdx.x * blockDim.x + threadIdx.x) >> 6; // global wave
    const int lane = threadIdx.x & 63;
    if (gw >= M_TOTAL + COUT) return;

    float4 v;
    unsigned short* dst;
    if (gw < N_COARSE) {
        v = *(const float4*)(x + (size_t)gw * CIN + lane * 4);
        dst = xb + (size_t)gw * CIN + lane * 4;
    } else if (gw < M_TOTAL) {
        const int j  = gw - N_COARSE;
        const int p0 = idx[2 * j];
        const int p1 = idx[2 * j + 1];
        float4 a = *(const float4*)(x + (size_t)p0 * CIN + lane * 4);
        float4 b = *(const float4*)(x + (size_t)p1 * CIN + lane * 4);
        v.x = (a.x + b.x) * 0.5f; v.y = (a.y + b.y) * 0.5f;
        v.z = (a.z + b.z) * 0.5f; v.w = (a.w + b.w) * 0.5f;
        dst = xb + (size_t)gw * CIN + lane * 4;
    } else {
        const int r = gw - M_TOTAL;
        v = *(const float4*)(W + (size_t)r * CIN + lane * 4);
        dst = wb + (size_t)r * CIN + lane * 4;
    }
    ushort4 o;
    o.x = f2bf(v.x); o.y = f2bf(v.y); o.z = f2bf(v.z); o.w = f2bf(v.w);
    *(ushort4*)dst = o;
}

// ---------------------------------------------------------------------------
// Phase 2: y = x_full @ W^T + b.  BM=128 x BN=256 tile, 8 waves (2M x 4N),
// global_load_lds(16B) staging with pre-swizzled GLOBAL source so the linear
// LDS image is XOR-swizzled for conflict-reduced ds_read_b128 (rule #21).
// ---------------------------------------------------------------------------
__global__ __launch_bounds__(512, 2) void gemm_kernel(
    const unsigned short* __restrict__ xb,   // [XB_ROWS][CIN] bf16
    const unsigned short* __restrict__ wb,   // [COUT][CIN] bf16
    const float* __restrict__ bias,          // [COUT]
    float*       __restrict__ out)           // [M_TOTAL][COUT]
{
    __shared__ __align__(16) unsigned short As[BM * BK];  // 16 KB
    __shared__ __align__(16) unsigned short Bs[BN * BK];  // 32 KB

    const int brow = blockIdx.x * BM;
    const int t    = threadIdx.x;
    const int lane = t & 63;
    const int wid  = t >> 6;      // 0..7
    const int wrr  = wid >> 2;    // 0..1  (64-row half)
    const int wcc  = wid & 3;     // 0..3  (64-col quarter)

    f32x4 acc[4][4];
#pragma unroll
    for (int i = 0; i < 4; ++i)
#pragma unroll
        for (int j = 0; j < 4; ++j)
            acc[i][j] = (f32x4){0.f, 0.f, 0.f, 0.f};

    const char* xbc = (const char*)xb;
    const char* wbc = (const char*)wb;

    for (int k0 = 0; k0 < CIN; k0 += BK) {
        // ---- stage A: 128x64 bf16 = 16 KB, 2 gload16 per wave ----
#pragma unroll
        for (int i = 0; i < 2; ++i) {
            const int r  = wid * 16 + i * 8 + (lane >> 3);
            const int cb = (lane & 7) * 16;
            const char* g = xbc + (size_t)(brow + r) * (CIN * 2) + k0 * 2
                              + (cb ^ ((r & 7) << 4));     // inverse-swizzle src
            GLOAD16(g, (char*)As + wid * 2048 + i * 1024);
        }
        // ---- stage B: 256x64 bf16 = 32 KB, 4 gload16 per wave ----
#pragma unroll
        for (int i = 0; i < 4; ++i) {
            const int r  = wid * 32 + i * 8 + (lane >> 3);
            const int cb = (lane & 7) * 16;
            const char* g = wbc + (size_t)r * (CIN * 2) + k0 * 2
                              + (cb ^ ((r & 7) << 4));
            GLOAD16(g, (char*)Bs + wid * 4096 + i * 1024);
        }
        __syncthreads();   // compiler drains vmcnt(0) before s_barrier

        // ---- MFMA over this K-slice ----
#pragma unroll
        for (int kk = 0; kk < BK; kk += 32) {
            const int vb = kk * 2 + ((lane >> 4) << 4);   // col-byte pre-swizzle
            bf16x8 af[4], bfv[4];
#pragma unroll
            for (int i = 0; i < 4; ++i) {
                const int r = wrr * 64 + i * 16 + (lane & 15);
                const char* p = (const char*)As + r * (BK * 2) + (vb ^ ((r & 7) << 4));
                af[i] = __builtin_bit_cast(bf16x8, *(const int4*)p);
            }
#pragma unroll
            for (int j = 0; j < 4; ++j) {
                const int r = wcc * 64 + j * 16 + (lane & 15);
                const char* p = (const char*)Bs + r * (BK * 2) + (vb ^ ((r & 7) << 4));
                bfv[j] = __builtin_bit_cast(bf16x8, *(const int4*)p);
            }
#pragma unroll
            for (int i = 0; i < 4; ++i)
#pragma unroll
                for (int j = 0; j < 4; ++j)
                    acc[i][j] = __builtin_amdgcn_mfma_f32_16x16x32_bf16(
                        af[i], bfv[j], acc[i][j], 0, 0, 0);
        }
        __syncthreads();
    }

    // ---- epilogue: bias + fp32 store ----
    // C/D layout: col = lane&15, row = (lane>>4)*4 + reg
    const int colbase = wcc * 64 + (lane & 15);
    const int rowbase = brow + wrr * 64 + ((lane >> 4) << 2);
#pragma unroll
    for (int j = 0; j < 4; ++j) {
        const int col = colbase + j * 16;
        const float bv = bias[col];
#pragma unroll
        for (int i = 0; i < 4; ++i) {
            const int row = rowbase + i * 16;
#pragma unroll
            for (int r2 = 0; r2 < 4; ++r2) {
                const int rr = row + r2;
                if (rr < M_TOTAL)
                    out[(size_t)rr * COUT + col] = acc[i][j][r2] + bv;
            }
        }
    }
}

// ---------------------------------------------------------------------------
// Fallback: round-1 fused kernel (used only if ws_size is too small).
// ---------------------------------------------------------------------------
union Pk8 { unsigned short h[8]; int4 v; };

__global__ __launch_bounds__(256, 2) void unpool_linear_fused(
    const float* __restrict__ x, const int* __restrict__ idx,
    const float* __restrict__ W, const float* __restrict__ bias,
    float* __restrict__ out)
{
    __shared__ __align__(16) unsigned short As[128 * 64];
    __shared__ __align__(16) unsigned short Bs[128 * 64];
    const int m0 = blockIdx.x * 128;
    const int n0 = blockIdx.y * 128;
    const int t = threadIdx.x, lane = t & 63, wid = t >> 6;
    const int wr = wid >> 1, wc = wid & 1;
    f32x4 acc[4][4];
#pragma unroll
    for (int i = 0; i < 4; ++i)
#pragma unroll
        for (int j = 0; j < 4; ++j) acc[i][j] = (f32x4){0.f,0.f,0.f,0.f};
    for (int k0 = 0; k0 < CIN; k0 += 64) {
#pragma unroll
        for (int i = 0; i < 4; ++i) {
            const int chunk = t + i * 256, r = chunk >> 3, c8 = chunk & 7;
            const int kcol = k0 + c8 * 8;
            const int sidx = (r * 64 + c8 * 8) ^ ((r & 7) << 3);
            float v[8];
            const int gr = m0 + r;
            if (gr < N_COARSE) {
                const float* src = x + (size_t)gr * CIN + kcol;
                float4 a0 = *(const float4*)(src), a1 = *(const float4*)(src + 4);
                v[0]=a0.x; v[1]=a0.y; v[2]=a0.z; v[3]=a0.w;
                v[4]=a1.x; v[5]=a1.y; v[6]=a1.z; v[7]=a1.w;
            } else if (gr < M_TOTAL) {
                const int j = gr - N_COARSE;
                const int p0 = idx[2*j], p1 = idx[2*j+1];
                const float* s0 = x + (size_t)p0 * CIN + kcol;
                const float* s1 = x + (size_t)p1 * CIN + kcol;
                float4 a0=*(const float4*)(s0), a1=*(const float4*)(s0+4);
                float4 b0=*(const float4*)(s1), b1=*(const float4*)(s1+4);
                v[0]=(a0.x+b0.x)*.5f; v[1]=(a0.y+b0.y)*.5f; v[2]=(a0.z+b0.z)*.5f; v[3]=(a0.w+b0.w)*.5f;
                v[4]=(a1.x+b1.x)*.5f; v[5]=(a1.y+b1.y)*.5f; v[6]=(a1.z+b1.z)*.5f; v[7]=(a1.w+b1.w)*.5f;
            } else {
#pragma unroll
                for (int q = 0; q < 8; ++q) v[q] = 0.f;
            }
            Pk8 pa;
#pragma unroll
            for (int q = 0; q < 8; ++q) pa.h[q] = f2bf(v[q]);
            *(int4*)&As[sidx] = pa.v;
            const float* ws = W + (size_t)(n0 + r) * CIN + kcol;
            float4 w0 = *(const float4*)(ws), w1 = *(const float4*)(ws + 4);
            Pk8 pb;
            pb.h[0]=f2bf(w0.x); pb.h[1]=f2bf(w0.y); pb.h[2]=f2bf(w0.z); pb.h[3]=f2bf(w0.w);
            pb.h[4]=f2bf(w1.x); pb.h[5]=f2bf(w1.y); pb.h[6]=f2bf(w1.z); pb.h[7]=f2bf(w1.w);
            *(int4*)&Bs[sidx] = pb.v;
        }
        __syncthreads();
#pragma unroll
        for (int kk = 0; kk < 64; kk += 32) {
            const int kcol = kk + 8 * (lane >> 4);
            bf16x8 af[4], bfv[4];
#pragma unroll
            for (int i = 0; i < 4; ++i) {
                const int r = wr * 64 + i * 16 + (lane & 15);
                af[i] = __builtin_bit_cast(bf16x8, *(const int4*)&As[(r*64+kcol) ^ ((r&7)<<3)]);
            }
#pragma unroll
            for (int j = 0; j < 4; ++j) {
                const int r = wc * 64 + j * 16 + (lane & 15);
                bfv[j] = __builtin_bit_cast(bf16x8, *(const int4*)&Bs[(r*64+kcol) ^ ((r&7)<<3)]);
            }
#pragma unroll
            for (int i = 0; i < 4; ++i)
#pragma unroll
                for (int j = 0; j < 4; ++j)
                    acc[i][j] = __builtin_amdgcn_mfma_f32_16x16x32_bf16(af[i], bfv[j], acc[i][j], 0, 0, 0);
        }
        __syncthreads();
    }
    const int colbase = n0 + wc * 64 + (lane & 15);
    const int rowbase = m0 + wr * 64 + ((lane >> 4) << 2);
#pragma unroll
    for (int j = 0; j < 4; ++j) {
        const int col = colbase + j * 16;
        const float bv = bias[col];
#pragma unroll
        for (int i = 0; i < 4; ++i) {
            const int row = rowbase + i * 16;
#pragma unroll
            for (int r2 = 0; r2 < 4; ++r2) {
                const int rr = row + r2;
                if (rr < M_TOTAL) out[(size_t)rr * COUT + col] = acc[i][j][r2] + bv;
            }
        }
    }
}

extern "C" void kernel_launch(void* const* d_in, const int* in_sizes, int n_in,
                              void* d_out, int out_size, void* d_ws, size_t ws_size,
                              hipStream_t stream) {
    const float* x    = (const float*)d_in[0];
    const int*   idx  = (const int*)d_in[1];
    const float* W    = (const float*)d_in[2];
    const float* bias = (const float*)d_in[3];
    float* out = (float*)d_out;

    if (ws_size >= XB_BYTES + WB_BYTES) {
        unsigned short* xb = (unsigned short*)d_ws;
        unsigned short* wb = (unsigned short*)((char*)d_ws + XB_BYTES);
        const int total_waves = M_TOTAL + COUT;              // 164098
        const int prep_blocks = (total_waves + 3) / 4;       // 41025
        prep_kernel<<<prep_blocks, 256, 0, stream>>>(x, idx, W, xb, wb);
        gemm_kernel<<<MT, 512, 0, stream>>>(xb, wb, bias, out);
    } else {
        dim3 grid(MT, COUT / 128);
        unpool_linear_fused<<<grid, 256, 0, stream>>>(x, idx, W, bias, out);
    }
}

// Round 3
// 100.128 us; speedup vs baseline: 1.3441x; 1.2128x over previous
//
#include <hip/hip_runtime.h>
#include <hip/hip_bf16.h>

// Problem constants (from reference)
#define N_COARSE 40962
#define N_NEW    122880
#define M_TOTAL  163842            // N_COARSE + N_NEW
#define CIN      256
#define COUT     256

// Tiling
#define BM    128
#define BK    32
#define NSTEP (CIN / BK)           // 8
#define MT    ((M_TOTAL + BM - 1) / BM)   // 1281
#define WB_BYTES ((size_t)COUT * CIN * 2) // 128 KB bf16 W in d_ws

typedef __bf16 bf16x8 __attribute__((ext_vector_type(8)));
typedef float  f32x4  __attribute__((ext_vector_type(4)));

static __device__ __forceinline__ unsigned short f2bf(float f) {
    unsigned int u = __builtin_bit_cast(unsigned int, f);
    u += 0x7FFFu + ((u >> 16) & 1u);   // round-to-nearest-even
    return (unsigned short)(u >> 16);
}

#define GLOAD16(gp, lp)                                                        \
    __builtin_amdgcn_global_load_lds(                                          \
        (const __attribute__((address_space(1))) unsigned int*)(gp),           \
        (__attribute__((address_space(3))) unsigned int*)(lp), 16, 0, 0)

// ---------------------------------------------------------------------------
// Tiny prep: W fp32 -> bf16 (wb in d_ws, 128 KB). 64 blocks x 256 thr x 4 elem.
// ---------------------------------------------------------------------------
__global__ __launch_bounds__(256) void wconv_kernel(
    const float* __restrict__ W, unsigned short* __restrict__ wb)
{
    const int i = (blockIdx.x * 256 + threadIdx.x) * 4;
    float4 v = *(const float4*)(W + i);
    ushort4 o;
    o.x = f2bf(v.x); o.y = f2bf(v.y); o.z = f2bf(v.z); o.w = f2bf(v.w);
    *(ushort4*)(wb + i) = o;
}

// ---------------------------------------------------------------------------
// Fused: gather/avg/convert A-tile once into LDS, stream W tiles (BK=32) via
// global_load_lds with pre-swizzled source, MFMA with swapped operands so the
// epilogue can store 1KB-contiguous rows via an LDS transpose.
// LDS: As 64 KB + Ws 16 KB = 80 KB -> 2 blocks/CU.
// ---------------------------------------------------------------------------
__global__ __launch_bounds__(512, 4) void unpool_gemm_kernel(
    const float* __restrict__ x,     // [N_COARSE][CIN] fp32
    const int*   __restrict__ idx,   // [N_NEW][2] int32
    const unsigned short* __restrict__ wb,  // [COUT][CIN] bf16
    const float* __restrict__ bias,  // [COUT] fp32
    float*       __restrict__ out)   // [M_TOTAL][COUT] fp32
{
    __shared__ __align__(16) unsigned short As[BM * CIN];   // 64 KB (swizzled)
    __shared__ __align__(16) unsigned short Ws[COUT * BK];  // 16 KB (swizzled)

    const int brow = blockIdx.x * BM;
    const int t    = threadIdx.x;
    const int lane = t & 63;
    const int wid  = t >> 6;      // 0..7
    const int wrr  = wid >> 2;    // 0..1  (64-row half of A)
    const int wcc  = wid & 3;     // 0..3  (64-col quarter of out)
    const char* wbc = (const char*)wb;

    // ---- issue W-tile 0 now; latency hides under the A gather ----
#pragma unroll
    for (int i = 0; i < 2; ++i) {
        const int o = wid * 2048 + i * 1024 + lane * 16;
        const int r = o >> 6, c = o & 63;
        GLOAD16(wbc + r * 512 + (c ^ (((r >> 1) & 3) << 4)), (char*)Ws + o);
    }

    // ---- A-stage: gather + average + bf16 convert, swizzled ds_write ----
    {
        const int r  = t >> 2;          // tile row 0..127 (4 threads/row)
        const int q  = t & 3;           // 64-col quarter
        const int gr = brow + r;
        int p0 = gr, p1 = gr;
        float sc = 0.5f;                // coarse: (a+a)*0.5 == a exactly
        if (gr >= M_TOTAL) { p0 = 0; p1 = 0; sc = 0.f; }
        else if (gr >= N_COARSE) {
            const int j = gr - N_COARSE;
            p0 = idx[2 * j]; p1 = idx[2 * j + 1];
        }
        const float* s0 = x + (size_t)p0 * CIN + q * 64;
        const float* s1 = x + (size_t)p1 * CIN + q * 64;
        char* arow = (char*)As + r * 512;
        const int swz = (r & 7) << 4;
#pragma unroll
        for (int c = 0; c < 4; ++c) {   // 16 cols per chunk
            float4 a0 = *(const float4*)(s0 + c * 16 + 0);
            float4 a1 = *(const float4*)(s0 + c * 16 + 4);
            float4 a2 = *(const float4*)(s0 + c * 16 + 8);
            float4 a3 = *(const float4*)(s0 + c * 16 + 12);
            float4 b0 = *(const float4*)(s1 + c * 16 + 0);
            float4 b1 = *(const float4*)(s1 + c * 16 + 4);
            float4 b2 = *(const float4*)(s1 + c * 16 + 8);
            float4 b3 = *(const float4*)(s1 + c * 16 + 12);
            union { unsigned short h[8]; int4 v; } lo, hi;
            lo.h[0] = f2bf((a0.x + b0.x) * sc); lo.h[1] = f2bf((a0.y + b0.y) * sc);
            lo.h[2] = f2bf((a0.z + b0.z) * sc); lo.h[3] = f2bf((a0.w + b0.w) * sc);
            lo.h[4] = f2bf((a1.x + b1.x) * sc); lo.h[5] = f2bf((a1.y + b1.y) * sc);
            lo.h[6] = f2bf((a1.z + b1.z) * sc); lo.h[7] = f2bf((a1.w + b1.w) * sc);
            hi.h[0] = f2bf((a2.x + b2.x) * sc); hi.h[1] = f2bf((a2.y + b2.y) * sc);
            hi.h[2] = f2bf((a2.z + b2.z) * sc); hi.h[3] = f2bf((a2.w + b2.w) * sc);
            hi.h[4] = f2bf((a3.x + b3.x) * sc); hi.h[5] = f2bf((a3.y + b3.y) * sc);
            hi.h[6] = f2bf((a3.z + b3.z) * sc); hi.h[7] = f2bf((a3.w + b3.w) * sc);
            const int cb = q * 128 + c * 32;    // byte col within 512B row
            *(int4*)(arow + ((cb +  0) ^ swz)) = lo.v;
            *(int4*)(arow + ((cb + 16) ^ swz)) = hi.v;
        }
    }

    f32x4 acc[4][4];   // acc[j][i]: j = W/N quadrant, i = A/M quadrant
#pragma unroll
    for (int j = 0; j < 4; ++j)
#pragma unroll
        for (int i = 0; i < 4; ++i)
            acc[j][i] = (f32x4){0.f, 0.f, 0.f, 0.f};

    // ---- K-loop: 8 steps of BK=32 ----
    for (int ks = 0; ks < NSTEP; ++ks) {
        __syncthreads();   // Ws[ks] (and As at ks=0) ready: drains vmcnt+lgkm

        bf16x8 af[4], wf[4];
        const int acb = ks * 64 + ((lane >> 4) << 4);
#pragma unroll
        for (int i = 0; i < 4; ++i) {
            const int ar = wrr * 64 + i * 16 + (lane & 15);
            af[i] = __builtin_bit_cast(bf16x8,
                *(const int4*)((const char*)As + ar * 512 + (acb ^ ((ar & 7) << 4))));
        }
        const int wcb = (lane >> 4) << 4;
#pragma unroll
        for (int j = 0; j < 4; ++j) {
            const int wr_ = wcc * 64 + j * 16 + (lane & 15);
            wf[j] = __builtin_bit_cast(bf16x8,
                *(const int4*)((const char*)Ws + wr_ * 64 + (wcb ^ (((wr_ >> 1) & 3) << 4))));
        }
        __syncthreads();   // all waves done reading Ws[ks]

        if (ks + 1 < NSTEP) {   // issue next W tile; flies during MFMA
#pragma unroll
            for (int i = 0; i < 2; ++i) {
                const int o = wid * 2048 + i * 1024 + lane * 16;
                const int r = o >> 6, c = o & 63;
                GLOAD16(wbc + r * 512 + (ks + 1) * 64 + (c ^ (((r >> 1) & 3) << 4)),
                        (char*)Ws + o);
            }
        }

        // swapped operands: lane&15 -> M row, (lane>>4)*4+reg -> N col
#pragma unroll
        for (int j = 0; j < 4; ++j)
#pragma unroll
            for (int i = 0; i < 4; ++i)
                acc[j][i] = __builtin_amdgcn_mfma_f32_16x16x32_bf16(
                    wf[j], af[i], acc[j][i], 0, 0, 0);
    }

    // ---- bias (each lane owns 4 consecutive n) ----
    const int nb = wcc * 64 + ((lane >> 4) << 2);
#pragma unroll
    for (int j = 0; j < 4; ++j) {
        const f32x4 bv = __builtin_bit_cast(f32x4, *(const float4*)(bias + nb + j * 16));
#pragma unroll
        for (int i = 0; i < 4; ++i)
            acc[j][i] = acc[j][i] + bv;
    }

    // ---- epilogue: LDS transpose (reuse As as [64][256] f32), 1KB stores ----
    float* Af = (float*)As;
    for (int h = 0; h < 2; ++h) {
        __syncthreads();
        if (wrr == h) {
#pragma unroll
            for (int j = 0; j < 4; ++j)
#pragma unroll
                for (int i = 0; i < 4; ++i) {
                    const int r  = i * 16 + (lane & 15);                  // 0..63
                    const int cb = wcc * 256 + j * 64 + ((lane >> 4) << 4); // byte col
                    *(f32x4*)((char*)Af + r * 1024 + (cb ^ ((r & 7) << 4))) = acc[j][i];
                }
        }
        __syncthreads();
#pragma unroll
        for (int ri = 0; ri < 8; ++ri) {
            const int r = wid * 8 + ri;
            const f32x4 v = *(const f32x4*)((const char*)Af + r * 1024 +
                                            ((lane * 16) ^ ((r & 7) << 4)));
            const int gr = brow + h * 64 + r;
            if (gr < M_TOTAL)
                *(f32x4*)((char*)out + (size_t)gr * 1024 + lane * 16) = v;
        }
    }
}

// ---------------------------------------------------------------------------
// Fallback (only if ws_size < 128 KB): round-1 fused kernel, known-correct.
// ---------------------------------------------------------------------------
union Pk8 { unsigned short h[8]; int4 v; };

__global__ __launch_bounds__(256, 2) void unpool_linear_fused(
    const float* __restrict__ x, const int* __restrict__ idx,
    const float* __restrict__ W, const float* __restrict__ bias,
    float* __restrict__ out)
{
    __shared__ __align__(16) unsigned short As[128 * 64];
    __shared__ __align__(16) unsigned short Bs[128 * 64];
    const int m0 = blockIdx.x * 128;
    const int n0 = blockIdx.y * 128;
    const int t = threadIdx.x, lane = t & 63, wid = t >> 6;
    const int wr = wid >> 1, wc = wid & 1;
    f32x4 acc[4][4];
#pragma unroll
    for (int i = 0; i < 4; ++i)
#pragma unroll
        for (int j = 0; j < 4; ++j) acc[i][j] = (f32x4){0.f,0.f,0.f,0.f};
    for (int k0 = 0; k0 < CIN; k0 += 64) {
#pragma unroll
        for (int i = 0; i < 4; ++i) {
            const int chunk = t + i * 256, r = chunk >> 3, c8 = chunk & 7;
            const int kcol = k0 + c8 * 8;
            const int sidx = (r * 64 + c8 * 8) ^ ((r & 7) << 3);
            float v[8];
            const int gr = m0 + r;
            if (gr < N_COARSE) {
                const float* src = x + (size_t)gr * CIN + kcol;
                float4 a0 = *(const float4*)(src), a1 = *(const float4*)(src + 4);
                v[0]=a0.x; v[1]=a0.y; v[2]=a0.z; v[3]=a0.w;
                v[4]=a1.x; v[5]=a1.y; v[6]=a1.z; v[7]=a1.w;
            } else if (gr < M_TOTAL) {
                const int j = gr - N_COARSE;
                const int p0 = idx[2*j], p1 = idx[2*j+1];
                const float* s0 = x + (size_t)p0 * CIN + kcol;
                const float* s1 = x + (size_t)p1 * CIN + kcol;
                float4 a0=*(const float4*)(s0), a1=*(const float4*)(s0+4);
                float4 b0=*(const float4*)(s1), b1=*(const float4*)(s1+4);
                v[0]=(a0.x+b0.x)*.5f; v[1]=(a0.y+b0.y)*.5f; v[2]=(a0.z+b0.z)*.5f; v[3]=(a0.w+b0.w)*.5f;
                v[4]=(a1.x+b1.x)*.5f; v[5]=(a1.y+b1.y)*.5f; v[6]=(a1.z+b1.z)*.5f; v[7]=(a1.w+b1.w)*.5f;
            } else {
#pragma unroll
                for (int q = 0; q < 8; ++q) v[q] = 0.f;
            }
            Pk8 pa;
#pragma unroll
            for (int q = 0; q < 8; ++q) pa.h[q] = f2bf(v[q]);
            *(int4*)&As[sidx] = pa.v;
            const float* ws = W + (size_t)(n0 + r) * CIN + kcol;
            float4 w0 = *(const float4*)(ws), w1 = *(const float4*)(ws + 4);
            Pk8 pb;
            pb.h[0]=f2bf(w0.x); pb.h[1]=f2bf(w0.y); pb.h[2]=f2bf(w0.z); pb.h[3]=f2bf(w0.w);
            pb.h[4]=f2bf(w1.x); pb.h[5]=f2bf(w1.y); pb.h[6]=f2bf(w1.z); pb.h[7]=f2bf(w1.w);
            *(int4*)&Bs[sidx] = pb.v;
        }
        __syncthreads();
#pragma unroll
        for (int kk = 0; kk < 64; kk += 32) {
            const int kcol = kk + 8 * (lane >> 4);
            bf16x8 af[4], bfv[4];
#pragma unroll
            for (int i = 0; i < 4; ++i) {
                const int r = wr * 64 + i * 16 + (lane & 15);
                af[i] = __builtin_bit_cast(bf16x8, *(const int4*)&As[(r*64+kcol) ^ ((r&7)<<3)]);
            }
#pragma unroll
            for (int j = 0; j < 4; ++j) {
                const int r = wc * 64 + j * 16 + (lane & 15);
                bfv[j] = __builtin_bit_cast(bf16x8, *(const int4*)&Bs[(r*64+kcol) ^ ((r&7)<<3)]);
            }
#pragma unroll
            for (int i = 0; i < 4; ++i)
#pragma unroll
                for (int j = 0; j < 4; ++j)
                    acc[i][j] = __builtin_amdgcn_mfma_f32_16x16x32_bf16(af[i], bfv[j], acc[i][j], 0, 0, 0);
        }
        __syncthreads();
    }
    const int colbase = n0 + wc * 64 + (lane & 15);
    const int rowbase = m0 + wr * 64 + ((lane >> 4) << 2);
#pragma unroll
    for (int j = 0; j < 4; ++j) {
        const int col = colbase + j * 16;
        const float bv = bias[col];
#pragma unroll
        for (int i = 0; i < 4; ++i) {
            const int row = rowbase + i * 16;
#pragma unroll
            for (int r2 = 0; r2 < 4; ++r2) {
                const int rr = row + r2;
                if (rr < M_TOTAL) out[(size_t)rr * COUT + col] = acc[i][j][r2] + bv;
            }
        }
    }
}

extern "C" void kernel_launch(void* const* d_in, const int* in_sizes, int n_in,
                              void* d_out, int out_size, void* d_ws, size_t ws_size,
                              hipStream_t stream) {
    const float* x    = (const float*)d_in[0];
    const int*   idx  = (const int*)d_in[1];
    const float* W    = (const float*)d_in[2];
    const float* bias = (const float*)d_in[3];
    float* out = (float*)d_out;

    if (ws_size >= WB_BYTES) {
        unsigned short* wb = (unsigned short*)d_ws;
        wconv_kernel<<<64, 256, 0, stream>>>(W, wb);
        unpool_gemm_kernel<<<MT, 512, 0, stream>>>(x, idx, wb, bias, out);
    } else {
        dim3 grid(MT, COUT / 128);
        unpool_linear_fused<<<grid, 256, 0, stream>>>(x, idx, W, bias, out);
    }
}

// Round 4
// 95.185 us; speedup vs baseline: 1.4139x; 1.0519x over previous
//
#include <hip/hip_runtime.h>
#include <hip/hip_bf16.h>

// Problem constants (from reference)
#define N_COARSE 40962
#define N_NEW    122880
#define M_TOTAL  163842            // N_COARSE + N_NEW
#define CIN      256
#define COUT     256

#define BK    32
#define NSTEP (CIN / BK)                  // 8
#define BM1   64
#define MT1   ((N_COARSE + BM1 - 1) / BM1)  // 641
#define WB_BYTES ((size_t)COUT * CIN * 2)   // 128 KB bf16 W in d_ws

typedef __bf16 bf16x8 __attribute__((ext_vector_type(8)));
typedef float  f32x4  __attribute__((ext_vector_type(4)));

static __device__ __forceinline__ unsigned short f2bf(float f) {
    unsigned int u = __builtin_bit_cast(unsigned int, f);
    u += 0x7FFFu + ((u >> 16) & 1u);   // round-to-nearest-even
    return (unsigned short)(u >> 16);
}

#define GLOAD16(gp, lp)                                                        \
    __builtin_amdgcn_global_load_lds(                                          \
        (const __attribute__((address_space(1))) unsigned int*)(gp),           \
        (__attribute__((address_space(3))) unsigned int*)(lp), 16, 0, 0)

// ---------------------------------------------------------------------------
// W fp32 -> bf16 (wb in d_ws, 128 KB).
// ---------------------------------------------------------------------------
__global__ __launch_bounds__(256) void wconv_kernel(
    const float* __restrict__ W, unsigned short* __restrict__ wb)
{
    const int i = (blockIdx.x * 256 + threadIdx.x) * 4;
    float4 v = *(const float4*)(W + i);
    ushort4 o;
    o.x = f2bf(v.x); o.y = f2bf(v.y); o.z = f2bf(v.z); o.w = f2bf(v.w);
    *(ushort4*)(wb + i) = o;
}

// ---------------------------------------------------------------------------
// Phase 1: y_coarse = x @ W^T + b for the 40962 coarse rows only.
// BM=64 x BN=256 tile, 8 waves (2Mx4N), W streamed via global_load_lds with
// pre-swizzled source; swapped MFMA operands + LDS-transpose epilogue for
// 1KB-contiguous stores. LDS: As 32 KB + Ws 16 KB = 48 KB -> 3 blocks/CU.
// ---------------------------------------------------------------------------
__global__ __launch_bounds__(512, 6) void coarse_gemm_kernel(
    const float* __restrict__ x,            // [N_COARSE][CIN] fp32
    const unsigned short* __restrict__ wb,  // [COUT][CIN] bf16
    const float* __restrict__ bias,         // [COUT]
    float*       __restrict__ out)          // rows [0, N_COARSE)
{
    __shared__ __align__(16) unsigned short As[BM1 * CIN];  // 32 KB (swizzled)
    __shared__ __align__(16) unsigned short Ws[COUT * BK];  // 16 KB (swizzled)

    const int brow = blockIdx.x * BM1;
    const int t    = threadIdx.x;
    const int lane = t & 63;
    const int wid  = t >> 6;      // 0..7
    const int wrr  = wid >> 2;    // 0..1  (32-row half of A)
    const int wcc  = wid & 3;     // 0..3  (64-col quarter of out)
    const char* wbc = (const char*)wb;

    // ---- issue W-tile 0 now; latency hides under the A stage ----
#pragma unroll
    for (int i = 0; i < 2; ++i) {
        const int o = wid * 2048 + i * 1024 + lane * 16;
        const int r = o >> 6, c = o & 63;
        GLOAD16(wbc + r * 512 + (c ^ (((r >> 1) & 3) << 4)), (char*)Ws + o);
    }

    // ---- A-stage: fp32 load + bf16 convert, swizzled ds_write ----
    {
        const int r  = t >> 3;          // tile row 0..63 (8 threads/row)
        const int q  = t & 7;           // 32-col chunk
        const int gr = brow + r;
        const int sr = (gr < N_COARSE) ? gr : 0;
        const float sc = (gr < N_COARSE) ? 1.f : 0.f;
        const float* s0 = x + (size_t)sr * CIN + q * 32;
        char* arow = (char*)As + r * 512;
        const int swz = (r & 7) << 4;
#pragma unroll
        for (int c = 0; c < 4; ++c) {   // 8 cols per chunk
            float4 a0 = *(const float4*)(s0 + c * 8 + 0);
            float4 a1 = *(const float4*)(s0 + c * 8 + 4);
            union { unsigned short h[8]; int4 v; } pk;
            pk.h[0] = f2bf(a0.x * sc); pk.h[1] = f2bf(a0.y * sc);
            pk.h[2] = f2bf(a0.z * sc); pk.h[3] = f2bf(a0.w * sc);
            pk.h[4] = f2bf(a1.x * sc); pk.h[5] = f2bf(a1.y * sc);
            pk.h[6] = f2bf(a1.z * sc); pk.h[7] = f2bf(a1.w * sc);
            *(int4*)(arow + ((q * 64 + c * 16) ^ swz)) = pk.v;
        }
    }

    f32x4 acc[4][2];   // acc[j][i]: j = N quadrant, i = M fragment
#pragma unroll
    for (int j = 0; j < 4; ++j)
#pragma unroll
        for (int i = 0; i < 2; ++i)
            acc[j][i] = (f32x4){0.f, 0.f, 0.f, 0.f};

    // ---- K-loop: 8 steps of BK=32 ----
    for (int ks = 0; ks < NSTEP; ++ks) {
        __syncthreads();   // Ws[ks] (and As at ks=0) ready

        bf16x8 af[2], wf[4];
        const int acb = ks * 64 + ((lane >> 4) << 4);
#pragma unroll
        for (int i = 0; i < 2; ++i) {
            const int ar = wrr * 32 + i * 16 + (lane & 15);
            af[i] = __builtin_bit_cast(bf16x8,
                *(const int4*)((const char*)As + ar * 512 + (acb ^ ((ar & 7) << 4))));
        }
        const int wcb = (lane >> 4) << 4;
#pragma unroll
        for (int j = 0; j < 4; ++j) {
            const int wr_ = wcc * 64 + j * 16 + (lane & 15);
            wf[j] = __builtin_bit_cast(bf16x8,
                *(const int4*)((const char*)Ws + wr_ * 64 + (wcb ^ (((wr_ >> 1) & 3) << 4))));
        }
        __syncthreads();   // all waves done reading Ws[ks]

        if (ks + 1 < NSTEP) {   // issue next W tile; flies during MFMA
#pragma unroll
            for (int i = 0; i < 2; ++i) {
                const int o = wid * 2048 + i * 1024 + lane * 16;
                const int r = o >> 6, c = o & 63;
                GLOAD16(wbc + r * 512 + (ks + 1) * 64 + (c ^ (((r >> 1) & 3) << 4)),
                        (char*)Ws + o);
            }
        }

        // swapped operands: lane&15 -> M row, (lane>>4)*4+reg -> N col
#pragma unroll
        for (int j = 0; j < 4; ++j)
#pragma unroll
            for (int i = 0; i < 2; ++i)
                acc[j][i] = __builtin_amdgcn_mfma_f32_16x16x32_bf16(
                    wf[j], af[i], acc[j][i], 0, 0, 0);
    }

    // ---- bias (each lane owns 4 consecutive n) ----
    const int nb = wcc * 64 + ((lane >> 4) << 2);
#pragma unroll
    for (int j = 0; j < 4; ++j) {
        const f32x4 bv = __builtin_bit_cast(f32x4, *(const float4*)(bias + nb + j * 16));
#pragma unroll
        for (int i = 0; i < 2; ++i)
            acc[j][i] = acc[j][i] + bv;
    }

    // ---- epilogue: LDS transpose (reuse As as [32][256] f32), 1KB stores ----
    float* Af = (float*)As;
    for (int h = 0; h < 2; ++h) {
        __syncthreads();
        if (wrr == h) {
#pragma unroll
            for (int j = 0; j < 4; ++j)
#pragma unroll
                for (int i = 0; i < 2; ++i) {
                    const int r  = i * 16 + (lane & 15);                    // 0..31
                    const int cb = wcc * 256 + j * 64 + ((lane >> 4) << 4); // byte col
                    *(f32x4*)((char*)Af + r * 1024 + (cb ^ ((r & 7) << 4))) = acc[j][i];
                }
        }
        __syncthreads();
#pragma unroll
        for (int ri = 0; ri < 4; ++ri) {
            const int r = wid * 4 + ri;
            const f32x4 v = *(const f32x4*)((const char*)Af + r * 1024 +
                                            ((lane * 16) ^ ((r & 7) << 4)));
            const int gr = brow + h * 32 + r;
            if (gr < N_COARSE)
                *(f32x4*)((char*)out + (size_t)gr * 1024 + lane * 16) = v;
        }
    }
}

// ---------------------------------------------------------------------------
// Phase 2: out[N_COARSE+j] = 0.5*(y_coarse[p0] + y_coarse[p1]).
// Pure streaming gather over the L3-resident coarse output. One row per wave
// per iteration; 8192 waves = full 32-wave/CU occupancy.
// ---------------------------------------------------------------------------
#define UNPOOL_WAVES 8192
__global__ __launch_bounds__(256) void unpool_kernel(
    const int* __restrict__ idx,    // [N_NEW][2]
    float*     __restrict__ out)
{
    const int wave = (blockIdx.x * 256 + threadIdx.x) >> 6;
    const int lane = threadIdx.x & 63;
    const float* yc = out;                              // coarse rows
    float* yo = out + (size_t)N_COARSE * CIN;           // new rows
#pragma unroll 2
    for (int j = wave; j < N_NEW; j += UNPOOL_WAVES) {
        const int p0 = idx[2 * j];
        const int p1 = idx[2 * j + 1];
        const float4 a = *(const float4*)(yc + (size_t)p0 * CIN + lane * 4);
        const float4 b = *(const float4*)(yc + (size_t)p1 * CIN + lane * 4);
        float4 o;
        o.x = (a.x + b.x) * 0.5f; o.y = (a.y + b.y) * 0.5f;
        o.z = (a.z + b.z) * 0.5f; o.w = (a.w + b.w) * 0.5f;
        *(float4*)(yo + (size_t)j * CIN + lane * 4) = o;
    }
}

// ---------------------------------------------------------------------------
// Fallback (only if ws_size < 128 KB): round-1 fused kernel, known-correct.
// ---------------------------------------------------------------------------
union Pk8 { unsigned short h[8]; int4 v; };

__global__ __launch_bounds__(256, 2) void unpool_linear_fused(
    const float* __restrict__ x, const int* __restrict__ idx,
    const float* __restrict__ W, const float* __restrict__ bias,
    float* __restrict__ out)
{
    __shared__ __align__(16) unsigned short As[128 * 64];
    __shared__ __align__(16) unsigned short Bs[128 * 64];
    const int m0 = blockIdx.x * 128;
    const int n0 = blockIdx.y * 128;
    const int t = threadIdx.x, lane = t & 63, wid = t >> 6;
    const int wr = wid >> 1, wc = wid & 1;
    f32x4 acc[4][4];
#pragma unroll
    for (int i = 0; i < 4; ++i)
#pragma unroll
        for (int j = 0; j < 4; ++j) acc[i][j] = (f32x4){0.f,0.f,0.f,0.f};
    for (int k0 = 0; k0 < CIN; k0 += 64) {
#pragma unroll
        for (int i = 0; i < 4; ++i) {
            const int chunk = t + i * 256, r = chunk >> 3, c8 = chunk & 7;
            const int kcol = k0 + c8 * 8;
            const int sidx = (r * 64 + c8 * 8) ^ ((r & 7) << 3);
            float v[8];
            const int gr = m0 + r;
            if (gr < N_COARSE) {
                const float* src = x + (size_t)gr * CIN + kcol;
                float4 a0 = *(const float4*)(src), a1 = *(const float4*)(src + 4);
                v[0]=a0.x; v[1]=a0.y; v[2]=a0.z; v[3]=a0.w;
                v[4]=a1.x; v[5]=a1.y; v[6]=a1.z; v[7]=a1.w;
            } else if (gr < M_TOTAL) {
                const int j = gr - N_COARSE;
                const int p0 = idx[2*j], p1 = idx[2*j+1];
                const float* s0 = x + (size_t)p0 * CIN + kcol;
                const float* s1 = x + (size_t)p1 * CIN + kcol;
                float4 a0=*(const float4*)(s0), a1=*(const float4*)(s0+4);
                float4 b0=*(const float4*)(s1), b1=*(const float4*)(s1+4);
                v[0]=(a0.x+b0.x)*.5f; v[1]=(a0.y+b0.y)*.5f; v[2]=(a0.z+b0.z)*.5f; v[3]=(a0.w+b0.w)*.5f;
                v[4]=(a1.x+b1.x)*.5f; v[5]=(a1.y+b1.y)*.5f; v[6]=(a1.z+b1.z)*.5f; v[7]=(a1.w+b1.w)*.5f;
            } else {
#pragma unroll
                for (int q = 0; q < 8; ++q) v[q] = 0.f;
            }
            Pk8 pa;
#pragma unroll
            for (int q = 0; q < 8; ++q) pa.h[q] = f2bf(v[q]);
            *(int4*)&As[sidx] = pa.v;
            const float* ws = W + (size_t)(n0 + r) * CIN + kcol;
            float4 w0 = *(const float4*)(ws), w1 = *(const float4*)(ws + 4);
            Pk8 pb;
            pb.h[0]=f2bf(w0.x); pb.h[1]=f2bf(w0.y); pb.h[2]=f2bf(w0.z); pb.h[3]=f2bf(w0.w);
            pb.h[4]=f2bf(w1.x); pb.h[5]=f2bf(w1.y); pb.h[6]=f2bf(w1.z); pb.h[7]=f2bf(w1.w);
            *(int4*)&Bs[sidx] = pb.v;
        }
        __syncthreads();
#pragma unroll
        for (int kk = 0; kk < 64; kk += 32) {
            const int kcol = kk + 8 * (lane >> 4);
            bf16x8 af[4], bfv[4];
#pragma unroll
            for (int i = 0; i < 4; ++i) {
                const int r = wr * 64 + i * 16 + (lane & 15);
                af[i] = __builtin_bit_cast(bf16x8, *(const int4*)&As[(r*64+kcol) ^ ((r&7)<<3)]);
            }
#pragma unroll
            for (int j = 0; j < 4; ++j) {
                const int r = wc * 64 + j * 16 + (lane & 15);
                bfv[j] = __builtin_bit_cast(bf16x8, *(const int4*)&Bs[(r*64+kcol) ^ ((r&7)<<3)]);
            }
#pragma unroll
            for (int i = 0; i < 4; ++i)
#pragma unroll
                for (int j = 0; j < 4; ++j)
                    acc[i][j] = __builtin_amdgcn_mfma_f32_16x16x32_bf16(af[i], bfv[j], acc[i][j], 0, 0, 0);
        }
        __syncthreads();
    }
    const int colbase = n0 + wc * 64 + (lane & 15);
    const int rowbase = m0 + wr * 64 + ((lane >> 4) << 2);
#pragma unroll
    for (int j = 0; j < 4; ++j) {
        const int col = colbase + j * 16;
        const float bv = bias[col];
#pragma unroll
        for (int i = 0; i < 4; ++i) {
            const int row = rowbase + i * 16;
#pragma unroll
            for (int r2 = 0; r2 < 4; ++r2) {
                const int rr = row + r2;
                if (rr < M_TOTAL) out[(size_t)rr * COUT + col] = acc[i][j][r2] + bv;
            }
        }
    }
}

extern "C" void kernel_launch(void* const* d_in, const int* in_sizes, int n_in,
                              void* d_out, int out_size, void* d_ws, size_t ws_size,
                              hipStream_t stream) {
    const float* x    = (const float*)d_in[0];
    const int*   idx  = (const int*)d_in[1];
    const float* W    = (const float*)d_in[2];
    const float* bias = (const float*)d_in[3];
    float* out = (float*)d_out;

    if (ws_size >= WB_BYTES) {
        unsigned short* wb = (unsigned short*)d_ws;
        wconv_kernel<<<64, 256, 0, stream>>>(W, wb);
        coarse_gemm_kernel<<<MT1, 512, 0, stream>>>(x, wb, bias, out);
        unpool_kernel<<<UNPOOL_WAVES / 4, 256, 0, stream>>>(idx, out);
    } else {
        dim3 grid((M_TOTAL + 127) / 128, COUT / 128);
        unpool_linear_fused<<<grid, 256, 0, stream>>>(x, idx, W, bias, out);
    }
}

// Round 5
// 76.283 us; speedup vs baseline: 1.7643x; 1.2478x over previous
//
#include <hip/hip_runtime.h>
#include <hip/hip_bf16.h>

// Problem constants (from reference)
#define N_COARSE 40962
#define N_NEW    122880
#define M_TOTAL  163842            // N_COARSE + N_NEW
#define CIN      256
#define COUT     256

#define BK    32
#define NSTEP (CIN / BK)                    // 8
#define BM    64
#define MT    ((M_TOTAL + BM - 1) / BM)     // 2561

#define XB_BYTES ((size_t)N_COARSE * CIN * 2)          // 20,972,544
#define WB_OFF   ((XB_BYTES + 255) & ~(size_t)255)
#define WB_BYTES ((size_t)COUT * CIN * 2)              // 131,072
#define WS_NEED  (WB_OFF + WB_BYTES)

#define XCH   (N_COARSE * CIN / 8)          // 1,310,784 x-chunks of 8 floats
#define WCH   (COUT * CIN / 8)              // 8,192 W-chunks
#define CVT_T (XCH + WCH)                   // 1,318,976 threads

typedef __bf16 bf16x8 __attribute__((ext_vector_type(8)));
typedef float  f32x4  __attribute__((ext_vector_type(4)));

static __device__ __forceinline__ unsigned short f2bf(float f) {
    unsigned int u = __builtin_bit_cast(unsigned int, f);
    u += 0x7FFFu + ((u >> 16) & 1u);   // round-to-nearest-even
    return (unsigned short)(u >> 16);
}

#define GLOAD16(gp, lp)                                                        \
    __builtin_amdgcn_global_load_lds(                                          \
        (const __attribute__((address_space(1))) unsigned int*)(gp),           \
        (__attribute__((address_space(3))) unsigned int*)(lp), 16, 0, 0)

// ---------------------------------------------------------------------------
// Convert x and W to bf16 (xb 21 MB + wb 128 KB in d_ws). Fully coalesced:
// 2 float4 loads -> 1 int4 store per thread.
// ---------------------------------------------------------------------------
__global__ __launch_bounds__(256) void conv_kernel(
    const float* __restrict__ x, const float* __restrict__ W,
    unsigned short* __restrict__ xb, unsigned short* __restrict__ wb)
{
    const int k = blockIdx.x * 256 + threadIdx.x;
    if (k >= CVT_T) return;
    const float* src;
    unsigned short* dst;
    int off;
    if (k < XCH) { src = x; dst = xb; off = k * 8; }
    else         { src = W; dst = wb; off = (k - XCH) * 8; }
    float4 v0 = *(const float4*)(src + off);
    float4 v1 = *(const float4*)(src + off + 4);
    union { unsigned short h[8]; int4 v; } p;
    p.h[0] = f2bf(v0.x); p.h[1] = f2bf(v0.y); p.h[2] = f2bf(v0.z); p.h[3] = f2bf(v0.w);
    p.h[4] = f2bf(v1.x); p.h[5] = f2bf(v1.y); p.h[6] = f2bf(v1.z); p.h[7] = f2bf(v1.w);
    *(int4*)(dst + off) = p.v;
}

// ---------------------------------------------------------------------------
// Fused GEMM over all 163842 rows. A-stage: coarse rows copied from xb,
// new rows gathered (2 parents, bf16 avg) from the 21 MB L2/L3-resident xb.
// Ws double-buffered (2x16 KB) with gloads issued at top-of-step so the
// barrier's vmcnt(0) drain never stalls. Swapped-operand MFMA + LDS
// transpose epilogue -> 1KB contiguous fp32 stores.
// LDS: As 32 KB + Ws 32 KB = 64 KB -> 2 blocks/CU (16 waves/CU).
// ---------------------------------------------------------------------------
__global__ __launch_bounds__(512, 4) void fused_gemm_kernel(
    const unsigned short* __restrict__ xb,   // [N_COARSE][CIN] bf16
    const int*   __restrict__ idx,           // [N_NEW][2]
    const unsigned short* __restrict__ wb,   // [COUT][CIN] bf16
    const float* __restrict__ bias,          // [COUT]
    float*       __restrict__ out)           // [M_TOTAL][COUT]
{
    __shared__ __align__(16) unsigned short As[BM * CIN];      // 32 KB (swizzled)
    __shared__ __align__(16) unsigned short Ws[2][COUT * BK];  // 2 x 16 KB

    const int brow = blockIdx.x * BM;
    const int t    = threadIdx.x;
    const int lane = t & 63;
    const int wid  = t >> 6;      // 0..7
    const int wrr  = wid >> 2;    // 0..1  (32-row half of A)
    const int wcc  = wid & 3;     // 0..3  (64-col quarter of out)
    const char* wbc = (const char*)wb;

    // ---- issue Ws[0] (K-step 0); latency hides under the A stage ----
#pragma unroll
    for (int i = 0; i < 2; ++i) {
        const int o = wid * 2048 + i * 1024 + lane * 16;
        const int r = o >> 6, c = o & 63;
        GLOAD16(wbc + r * 512 + (c ^ (((r >> 1) & 3) << 4)), (char*)Ws[0] + o);
    }

    // ---- A-stage: copy (coarse) or gather+avg (new), swizzled ds_write ----
    {
        const int r  = t >> 3;          // tile row 0..63 (8 threads/row)
        const int q  = t & 7;           // 32-col chunk (64B)
        const int gr = brow + r;
        char* arow = (char*)As + r * 512;
        const int swz = (r & 7) << 4;
        const int cb0 = q * 64;
        if (gr < N_COARSE || gr >= M_TOTAL) {
            const int sr = (gr < N_COARSE) ? gr : 0;   // pad rows: junk, unstored
            const char* s = (const char*)xb + (size_t)sr * 512 + cb0;
#pragma unroll
            for (int c = 0; c < 4; ++c)
                *(int4*)(arow + ((cb0 + c * 16) ^ swz)) = *(const int4*)(s + c * 16);
        } else {
            const int j  = gr - N_COARSE;
            const int p0 = idx[2 * j];
            const int p1 = idx[2 * j + 1];
            const char* s0 = (const char*)xb + (size_t)p0 * 512 + cb0;
            const char* s1 = (const char*)xb + (size_t)p1 * 512 + cb0;
#pragma unroll
            for (int c = 0; c < 4; ++c) {
                int4 a = *(const int4*)(s0 + c * 16);
                int4 b = *(const int4*)(s1 + c * 16);
                const unsigned int* au = (const unsigned int*)&a;
                const unsigned int* bu = (const unsigned int*)&b;
                union { unsigned short h[8]; int4 v; } p;
#pragma unroll
                for (int e = 0; e < 4; ++e) {
                    const float alo = __builtin_bit_cast(float, au[e] << 16);
                    const float ahi = __builtin_bit_cast(float, au[e] & 0xFFFF0000u);
                    const float blo = __builtin_bit_cast(float, bu[e] << 16);
                    const float bhi = __builtin_bit_cast(float, bu[e] & 0xFFFF0000u);
                    p.h[2 * e]     = f2bf((alo + blo) * 0.5f);
                    p.h[2 * e + 1] = f2bf((ahi + bhi) * 0.5f);
                }
                *(int4*)(arow + ((cb0 + c * 16) ^ swz)) = p.v;
            }
        }
    }

    f32x4 acc[4][2];   // acc[j][i]: j = N quadrant, i = M fragment
#pragma unroll
    for (int j = 0; j < 4; ++j)
#pragma unroll
        for (int i = 0; i < 2; ++i)
            acc[j][i] = (f32x4){0.f, 0.f, 0.f, 0.f};

    __syncthreads();   // As + Ws[0] ready (drains vmcnt + lgkm)

    // ---- K-loop: 8 steps of BK=32, Ws double-buffered ----
    for (int ks = 0; ks < NSTEP; ++ks) {
        const int cur = ks & 1;
        if (ks + 1 < NSTEP) {   // issue next W tile into the free buffer NOW
#pragma unroll
            for (int i = 0; i < 2; ++i) {
                const int o = wid * 2048 + i * 1024 + lane * 16;
                const int r = o >> 6, c = o & 63;
                GLOAD16(wbc + r * 512 + (ks + 1) * 64 + (c ^ (((r >> 1) & 3) << 4)),
                        (char*)Ws[cur ^ 1] + o);
            }
        }

        bf16x8 af[2], wf[4];
        const int acb = ks * 64 + ((lane >> 4) << 4);
#pragma unroll
        for (int i = 0; i < 2; ++i) {
            const int ar = wrr * 32 + i * 16 + (lane & 15);
            af[i] = __builtin_bit_cast(bf16x8,
                *(const int4*)((const char*)As + ar * 512 + (acb ^ ((ar & 7) << 4))));
        }
        const int wcb = (lane >> 4) << 4;
#pragma unroll
        for (int jj = 0; jj < 4; ++jj) {
            const int wr_ = wcc * 64 + jj * 16 + (lane & 15);
            wf[jj] = __builtin_bit_cast(bf16x8,
                *(const int4*)((const char*)Ws[cur] + wr_ * 64 + (wcb ^ (((wr_ >> 1) & 3) << 4))));
        }

        // swapped operands: lane&15 -> M row, (lane>>4)*4+reg -> N col
#pragma unroll
        for (int jj = 0; jj < 4; ++jj)
#pragma unroll
            for (int i = 0; i < 2; ++i)
                acc[jj][i] = __builtin_amdgcn_mfma_f32_16x16x32_bf16(
                    wf[jj], af[i], acc[jj][i], 0, 0, 0);

        __syncthreads();   // readers done with Ws[cur]; Ws[cur^1] DMA drained
    }

    // ---- bias (each lane owns 4 consecutive n) ----
    const int nb = wcc * 64 + ((lane >> 4) << 2);
#pragma unroll
    for (int j = 0; j < 4; ++j) {
        const f32x4 bv = __builtin_bit_cast(f32x4, *(const float4*)(bias + nb + j * 16));
#pragma unroll
        for (int i = 0; i < 2; ++i)
            acc[j][i] = acc[j][i] + bv;
    }

    // ---- epilogue: LDS transpose (reuse As as [32][256] f32), 1KB stores ----
    float* Af = (float*)As;
    for (int h = 0; h < 2; ++h) {
        __syncthreads();
        if (wrr == h) {
#pragma unroll
            for (int j = 0; j < 4; ++j)
#pragma unroll
                for (int i = 0; i < 2; ++i) {
                    const int r  = i * 16 + (lane & 15);                    // 0..31
                    const int cb = wcc * 256 + j * 64 + ((lane >> 4) << 4); // byte col
                    *(f32x4*)((char*)Af + r * 1024 + (cb ^ ((r & 7) << 4))) = acc[j][i];
                }
        }
        __syncthreads();
#pragma unroll
        for (int ri = 0; ri < 4; ++ri) {
            const int r = wid * 4 + ri;
            const f32x4 v = *(const f32x4*)((const char*)Af + r * 1024 +
                                            ((lane * 16) ^ ((r & 7) << 4)));
            const int gr = brow + h * 32 + r;
            if (gr < M_TOTAL)
                *(f32x4*)((char*)out + (size_t)gr * 1024 + lane * 16) = v;
        }
    }
}

// ---------------------------------------------------------------------------
// Fallback (only if ws too small): round-1 fused kernel, known-correct.
// ---------------------------------------------------------------------------
union Pk8 { unsigned short h[8]; int4 v; };

__global__ __launch_bounds__(256, 2) void unpool_linear_fused(
    const float* __restrict__ x, const int* __restrict__ idx,
    const float* __restrict__ W, const float* __restrict__ bias,
    float* __restrict__ out)
{
    __shared__ __align__(16) unsigned short As[128 * 64];
    __shared__ __align__(16) unsigned short Bs[128 * 64];
    const int m0 = blockIdx.x * 128;
    const int n0 = blockIdx.y * 128;
    const int t = threadIdx.x, lane = t & 63, wid = t >> 6;
    const int wr = wid >> 1, wc = wid & 1;
    f32x4 acc[4][4];
#pragma unroll
    for (int i = 0; i < 4; ++i)
#pragma unroll
        for (int j = 0; j < 4; ++j) acc[i][j] = (f32x4){0.f,0.f,0.f,0.f};
    for (int k0 = 0; k0 < CIN; k0 += 64) {
#pragma unroll
        for (int i = 0; i < 4; ++i) {
            const int chunk = t + i * 256, r = chunk >> 3, c8 = chunk & 7;
            const int kcol = k0 + c8 * 8;
            const int sidx = (r * 64 + c8 * 8) ^ ((r & 7) << 3);
            float v[8];
            const int gr = m0 + r;
            if (gr < N_COARSE) {
                const float* src = x + (size_t)gr * CIN + kcol;
                float4 a0 = *(const float4*)(src), a1 = *(const float4*)(src + 4);
                v[0]=a0.x; v[1]=a0.y; v[2]=a0.z; v[3]=a0.w;
                v[4]=a1.x; v[5]=a1.y; v[6]=a1.z; v[7]=a1.w;
            } else if (gr < M_TOTAL) {
                const int j = gr - N_COARSE;
                const int p0 = idx[2*j], p1 = idx[2*j+1];
                const float* s0 = x + (size_t)p0 * CIN + kcol;
                const float* s1 = x + (size_t)p1 * CIN + kcol;
                float4 a0=*(const float4*)(s0), a1=*(const float4*)(s0+4);
                float4 b0=*(const float4*)(s1), b1=*(const float4*)(s1+4);
                v[0]=(a0.x+b0.x)*.5f; v[1]=(a0.y+b0.y)*.5f; v[2]=(a0.z+b0.z)*.5f; v[3]=(a0.w+b0.w)*.5f;
                v[4]=(a1.x+b1.x)*.5f; v[5]=(a1.y+b1.y)*.5f; v[6]=(a1.z+b1.z)*.5f; v[7]=(a1.w+b1.w)*.5f;
            } else {
#pragma unroll
                for (int q = 0; q < 8; ++q) v[q] = 0.f;
            }
            Pk8 pa;
#pragma unroll
            for (int q = 0; q < 8; ++q) pa.h[q] = f2bf(v[q]);
            *(int4*)&As[sidx] = pa.v;
            const float* ws = W + (size_t)(n0 + r) * CIN + kcol;
            float4 w0 = *(const float4*)(ws), w1 = *(const float4*)(ws + 4);
            Pk8 pb;
            pb.h[0]=f2bf(w0.x); pb.h[1]=f2bf(w0.y); pb.h[2]=f2bf(w0.z); pb.h[3]=f2bf(w0.w);
            pb.h[4]=f2bf(w1.x); pb.h[5]=f2bf(w1.y); pb.h[6]=f2bf(w1.z); pb.h[7]=f2bf(w1.w);
            *(int4*)&Bs[sidx] = pb.v;
        }
        __syncthreads();
#pragma unroll
        for (int kk = 0; kk < 64; kk += 32) {
            const int kcol = kk + 8 * (lane >> 4);
            bf16x8 af[4], bfv[4];
#pragma unroll
            for (int i = 0; i < 4; ++i) {
                const int r = wr * 64 + i * 16 + (lane & 15);
                af[i] = __builtin_bit_cast(bf16x8, *(const int4*)&As[(r*64+kcol) ^ ((r&7)<<3)]);
            }
#pragma unroll
            for (int j = 0; j < 4; ++j) {
                const int r = wc * 64 + j * 16 + (lane & 15);
                bfv[j] = __builtin_bit_cast(bf16x8, *(const int4*)&Bs[(r*64+kcol) ^ ((r&7)<<3)]);
            }
#pragma unroll
            for (int i = 0; i < 4; ++i)
#pragma unroll
                for (int j = 0; j < 4; ++j)
                    acc[i][j] = __builtin_amdgcn_mfma_f32_16x16x32_bf16(af[i], bfv[j], acc[i][j], 0, 0, 0);
        }
        __syncthreads();
    }
    const int colbase = n0 + wc * 64 + (lane & 15);
    const int rowbase = m0 + wr * 64 + ((lane >> 4) << 2);
#pragma unroll
    for (int j = 0; j < 4; ++j) {
        const int col = colbase + j * 16;
        const float bv = bias[col];
#pragma unroll
        for (int i = 0; i < 4; ++i) {
            const int row = rowbase + i * 16;
#pragma unroll
            for (int r2 = 0; r2 < 4; ++r2) {
                const int rr = row + r2;
                if (rr < M_TOTAL) out[(size_t)rr * COUT + col] = acc[i][j][r2] + bv;
            }
        }
    }
}

extern "C" void kernel_launch(void* const* d_in, const int* in_sizes, int n_in,
                              void* d_out, int out_size, void* d_ws, size_t ws_size,
                              hipStream_t stream) {
    const float* x    = (const float*)d_in[0];
    const int*   idx  = (const int*)d_in[1];
    const float* W    = (const float*)d_in[2];
    const float* bias = (const float*)d_in[3];
    float* out = (float*)d_out;

    if (ws_size >= WS_NEED) {
        unsigned short* xb = (unsigned short*)d_ws;
        unsigned short* wb = (unsigned short*)((char*)d_ws + WB_OFF);
        conv_kernel<<<(CVT_T + 255) / 256, 256, 0, stream>>>(x, W, xb, wb);
        fused_gemm_kernel<<<MT, 512, 0, stream>>>(xb, idx, wb, bias, out);
    } else {
        dim3 grid((M_TOTAL + 127) / 128, COUT / 128);
        unpool_linear_fused<<<grid, 256, 0, stream>>>(x, idx, W, bias, out);
    }
}